// Round 13
// baseline (140.897 us; speedup 1.0000x reference)
//
#include <hip/hip_runtime.h>
#include <hip/hip_bf16.h>
#include <stdint.h>

typedef _Float16 f16x8 __attribute__((ext_vector_type(8)));
typedef __fp16 hf2 __attribute__((ext_vector_type(2)));
typedef float f32x4 __attribute__((ext_vector_type(4)));
typedef unsigned int u32x4 __attribute__((ext_vector_type(4)));
typedef unsigned int u32x2 __attribute__((ext_vector_type(2)));

#define N_ATOMS 262144
#define NSYM 4
#define NIMG 1024
#define FIXSCALE 1073741824.0f  // 2^30

// ---------- kernel 1: per-block symbol counts ----------
__global__ void hist_kernel(const int* __restrict__ sym, int* __restrict__ wbh) {
  int b = blockIdx.x;
  int i = b * 256 + threadIdx.x;
  int lane = threadIdx.x & 63, wave = threadIdx.x >> 6;
  __shared__ int wcnt[4][NSYM];
  int s = sym[i];
#pragma unroll
  for (int t = 0; t < NSYM; ++t) {
    unsigned long long m = __ballot(s == t);
    if (lane == 0) wcnt[wave][t] = __popcll(m);
  }
  __syncthreads();
  if (threadIdx.x < NSYM)
    wbh[b * 4 + threadIdx.x] = wcnt[0][threadIdx.x] + wcnt[1][threadIdx.x] +
                               wcnt[2][threadIdx.x] + wcnt[3][threadIdx.x];
}

// ---------- kernel 2 (fused): block 0 = scan->offsets/bases/pad-fill;
//            blocks 1..512 = wconv (fp16 pre-swizzled planes);
//            block 513 = zero the int64 image accumulators ----------
__global__ void fusedprep_kernel(const int* __restrict__ wbh, int* __restrict__ bases,
                                 int* __restrict__ offs, int* __restrict__ perm,
                                 const float* __restrict__ W1, const float* __restrict__ W2,
                                 unsigned short* __restrict__ wt,
                                 unsigned long long* __restrict__ acc64) {
  if (blockIdx.x >= 1 && blockIdx.x <= 512) {
    int idx = (blockIdx.x - 1) * 256 + threadIdx.x;  // 0..131071
    int t = idx >> 14;
    int layer = t >> 2, s = t & 3;
    int rem = idx & 16383;
    int h = rem >> 7, u = rem & 127;
    int gs = u >> 3, j = u & 7;
    int d = ((gs ^ (h & 7)) << 3) + j;
    const float* W = layer ? W2 : W1;
    _Float16 hv = (_Float16)W[(s * 128 + d) * 128 + h];  // RNE
    wt[t * 16384 + h * 128 + u] = __builtin_bit_cast(unsigned short, hv);
    return;
  }
  if (blockIdx.x == 513) {
#pragma unroll
    for (int k = 0; k < 4; ++k) acc64[threadIdx.x * 4 + k] = 0ull;
    return;
  }
  // blockIdx 0: offsets scan
  __shared__ int wtot[4][NSYM];
  __shared__ int offsh[NSYM + 1];
  __shared__ int totsh[NSYM];
  int t = threadIdx.x, lane = t & 63, wave = t >> 6;
  int pre[4][NSYM];
  int sum[NSYM] = {0, 0, 0, 0};
#pragma unroll
  for (int k = 0; k < 4; ++k)
#pragma unroll
    for (int s2 = 0; s2 < NSYM; ++s2) {
      pre[k][s2] = sum[s2];
      sum[s2] += wbh[(t * 4 + k) * 4 + s2];
    }
  int inc[NSYM] = {sum[0], sum[1], sum[2], sum[3]};
  for (int d = 1; d < 64; d <<= 1) {
#pragma unroll
    for (int s2 = 0; s2 < NSYM; ++s2) {
      int v = __shfl_up(inc[s2], d);
      if (lane >= d) inc[s2] += v;
    }
  }
  if (lane == 63)
#pragma unroll
    for (int s2 = 0; s2 < NSYM; ++s2) wtot[wave][s2] = inc[s2];
  __syncthreads();
  int wb[NSYM];
#pragma unroll
  for (int s2 = 0; s2 < NSYM; ++s2) {
    wb[s2] = 0;
    for (int w = 0; w < wave; ++w) wb[s2] += wtot[w][s2];
  }
  if (t == 255)
#pragma unroll
    for (int s2 = 0; s2 < NSYM; ++s2) totsh[s2] = wb[s2] + inc[s2];
  __syncthreads();
  if (t == 0) {
    int o = 0;
    offsh[0] = 0; offs[0] = 0;
    for (int s2 = 0; s2 < NSYM; ++s2) {
      o += (totsh[s2] + 255) & ~255;
      offsh[s2 + 1] = o; offs[s2 + 1] = o;
    }
  }
  __syncthreads();
#pragma unroll
  for (int k = 0; k < 4; ++k)
#pragma unroll
    for (int s2 = 0; s2 < NSYM; ++s2)
      bases[(t * 4 + k) * 4 + s2] = offsh[s2] + wb[s2] + (inc[s2] - sum[s2]) + pre[k][s2];
  for (int s2 = 0; s2 < NSYM; ++s2) {
    int lo = offsh[s2] + totsh[s2], hi = offsh[s2 + 1];
    for (int i = lo + t; i < hi; i += 256) perm[i] = -1;
  }
}

// ---------- kernel 3: deterministic scatter (perm only) ----------
__global__ void scatter_kernel(const int* __restrict__ sym, const int* __restrict__ bases,
                               int* __restrict__ perm) {
  int b = blockIdx.x;
  int i = b * 256 + threadIdx.x;
  int lane = threadIdx.x & 63, wave = threadIdx.x >> 6;
  __shared__ int wcnt[4][NSYM];
  int s = sym[i];
  unsigned long long mymask = 0;
#pragma unroll
  for (int t = 0; t < NSYM; ++t) {
    unsigned long long m = __ballot(s == t);
    if (lane == 0) wcnt[wave][t] = __popcll(m);
    if (s == t) mymask = m;
  }
  __syncthreads();
  int off = bases[b * 4 + s];
  for (int w = 0; w < wave; ++w) off += wcnt[w][s];
  off += __popcll(mymask & ((1ull << lane) - 1ull));
  perm[off] = i;
}

// ---------- kernel 4: fused 2-layer MLP + deterministic fixed-point segsum ----------
// 256 blocks x 8 waves x 32 atoms. LDS 128KB: W1h[0,32K) W2h[32K,64K) once;
// stage/bounce 8KB/wave. Dense 512B x-row loads; T14 prefetch issued right after
// stage-read (covers L1+bounce+L2). setprio(1) around MFMA clusters. Epilogue
// adds e*2^30 to acc64[img] via int64 atomics (associative -> deterministic).
__global__ __launch_bounds__(512, 2) void mlp_gemm(
    const float* __restrict__ x, const unsigned short* __restrict__ wt,
    const int* __restrict__ perm, const int* __restrict__ offs,
    const float* __restrict__ b1, const float* __restrict__ b2,
    const float* __restrict__ W3, const float* __restrict__ b3,
    const float* __restrict__ slope, const float* __restrict__ intercept,
    const int* __restrict__ img, unsigned long long* __restrict__ acc64) {
  extern __shared__ char lds[];  // 128 KB

  int s = blockIdx.x >> 6;
  int kblk = blockIdx.x & 63;
  int base = offs[s];
  int T = (offs[s + 1] - base) >> 8;

  int tid = threadIdx.x;
  int wave = tid >> 6, lane = tid & 63;
  int r0 = lane & 15, chunk = lane >> 4;
  int l32 = lane & 31, half = lane >> 5;
  char* stage = lds + 65536 + wave * 8192;

  const unsigned short* w1p = wt + (size_t)(0 + s) * 16384;
  const unsigned short* w2p = wt + (size_t)(4 + s) * 16384;

#pragma unroll
  for (int it = 0; it < 8; ++it) {
    int gb = it * 512 + wave * 64;
    const unsigned short* src = (gb >= 2048) ? (w2p + (size_t)(gb - 2048 + lane) * 8)
                                             : (w1p + (size_t)(gb + lane) * 8);
    __builtin_amdgcn_global_load_lds((const unsigned int*)src,
                                     (unsigned int*)(lds + (size_t)gb * 16), 16, 0, 0);
  }

  float b1v[8], b2v[8], w3v[8];
#pragma unroll
  for (int cf = 0; cf < 8; ++cf) {
    b1v[cf] = b1[s * 128 + cf * 16 + r0];
    b2v[cf] = b2[s * 128 + cf * 16 + r0];
    w3v[cf] = W3[s * 128 + cf * 16 + r0];
  }
  float sl = slope[s], ic = intercept[s], bb = b3[s];

  int cur_perm = (kblk < T) ? perm[base + (kblk << 8) + wave * 32 + l32] : -1;
  float4 raw[16];
#pragma unroll
  for (int it = 0; it < 16; ++it) {
    int atom = __shfl(cur_perm, it * 2 + half);
    raw[it] = *(const float4*)(x + (size_t)(atom < 0 ? 0 : atom) * 128 + l32 * 4);
  }

  __syncthreads();  // W staged

  f32x4 zero4 = {0.f, 0.f, 0.f, 0.f};

  for (int t = kblk; t < T; t += 64) {
    int tn = t + 64;
    int nperm = -1;
    if (tn < T) nperm = perm[base + (tn << 8) + wave * 32 + l32];

    // ---- stage-write: cvt fp16 + swizzled ds_write (consumes raw) ----
#pragma unroll
    for (int it = 0; it < 16; ++it) {
      int row = it * 2 + half;
      hf2 p0 = __builtin_amdgcn_cvt_pkrtz(raw[it].x, raw[it].y);
      hf2 p1 = __builtin_amdgcn_cvt_pkrtz(raw[it].z, raw[it].w);
      u32x2 w2 = {__builtin_bit_cast(unsigned int, p0), __builtin_bit_cast(unsigned int, p1)};
      int gs = (l32 >> 1) ^ (row & 7);
      *(u32x2*)(stage + row * 256 + gs * 16 + (l32 & 1) * 8) = w2;
    }
    // ---- stage-read: A fragments ----
    f16x8 ah[8];
#pragma unroll
    for (int rf = 0; rf < 2; ++rf)
#pragma unroll
      for (int kk = 0; kk < 4; ++kk) {
        int row = rf * 16 + r0;
        ah[rf * 4 + kk] = *(const f16x8*)(stage + row * 256 +
                                          (((kk * 4 + chunk) ^ (row & 7)) << 4));
      }

    // ---- T14: issue next tile's dense row loads NOW (covers L1+bounce+L2) ----
    if (tn < T) {
#pragma unroll
      for (int it = 0; it < 16; ++it) {
        int atom = __shfl(nperm, it * 2 + half);
        raw[it] = *(const float4*)(x + (size_t)(atom < 0 ? 0 : atom) * 128 + l32 * 4);
      }
    }

    // ---- layer 1: acc = x * W1h ----
    f32x4 acc[2][8];
#pragma unroll
    for (int i = 0; i < 2; ++i)
#pragma unroll
      for (int j = 0; j < 8; ++j) acc[i][j] = zero4;

    __builtin_amdgcn_s_setprio(1);
#pragma unroll
    for (int k = 0; k < 4; ++k)
#pragma unroll
      for (int cf = 0; cf < 8; ++cf) {
        int row = cf * 16 + r0;
        f16x8 bh = *(const f16x8*)(lds + row * 256 +
                                   ((((k * 4 + chunk)) << 4) ^ ((row & 7) << 4)));
        acc[0][cf] = __builtin_amdgcn_mfma_f32_16x16x32_f16(ah[k], bh, acc[0][cf], 0, 0, 0);
        acc[1][cf] = __builtin_amdgcn_mfma_f32_16x16x32_f16(ah[4 + k], bh, acc[1][cf], 0, 0, 0);
      }
    __builtin_amdgcn_s_setprio(0);

    // ---- bounce: h1 = relu(acc+b1) -> fp16, 2 half-passes ----
#pragma unroll
    for (int hp2 = 0; hp2 < 2; ++hp2) {
#pragma unroll
      for (int cf4 = 0; cf4 < 4; ++cf4) {
        int cf = hp2 * 4 + cf4;
        float bias = b1v[cf];
        int colp = cf4 * 16 + r0;
#pragma unroll
        for (int rf = 0; rf < 2; ++rf)
#pragma unroll
          for (int rr = 0; rr < 4; ++rr) {
            int row = rf * 16 + chunk * 4 + rr;
            float v = fmaxf(acc[rf][cf][rr] + bias, 0.f);
            unsigned short h = __builtin_bit_cast(unsigned short, (_Float16)v);  // RNE
            int cc = colp ^ (chunk << 4) ^ (rr << 2);
            *(unsigned int*)(stage + row * 256 + cc * 4) = ((unsigned int)h << 16) | h;
          }
      }
#pragma unroll
      for (int kk2 = 0; kk2 < 2; ++kk2) {
        int kk = hp2 * 2 + kk2;
#pragma unroll
        for (int rf = 0; rf < 2; ++rf) {
          int row = rf * 16 + r0;
          int xr3 = ((r0 >> 2) << 4) ^ ((r0 & 3) << 2);
          int c0 = kk2 * 32 + chunk * 8;
          u32x4 pa = *(const u32x4*)(stage + row * 256 + (c0 ^ xr3) * 4);
          u32x4 pb = *(const u32x4*)(stage + row * 256 + ((c0 + 4) ^ xr3) * 4);
          unsigned int h01 = (pa[0] >> 16) | (pa[1] & 0xffff0000u);
          unsigned int h23 = (pa[2] >> 16) | (pa[3] & 0xffff0000u);
          unsigned int h45 = (pb[0] >> 16) | (pb[1] & 0xffff0000u);
          unsigned int h67 = (pb[2] >> 16) | (pb[3] & 0xffff0000u);
          u32x4 hq = {h01, h23, h45, h67};
          ah[rf * 4 + kk] = __builtin_bit_cast(f16x8, hq);
        }
      }
    }

    // ---- layer 2: acc = h1 * W2h ----
#pragma unroll
    for (int i = 0; i < 2; ++i)
#pragma unroll
      for (int j = 0; j < 8; ++j) acc[i][j] = zero4;

    __builtin_amdgcn_s_setprio(1);
#pragma unroll
    for (int k = 0; k < 4; ++k)
#pragma unroll
      for (int cf = 0; cf < 8; ++cf) {
        int row = cf * 16 + r0;
        f16x8 bh = *(const f16x8*)(lds + 32768 + row * 256 +
                                   ((((k * 4 + chunk)) << 4) ^ ((row & 7) << 4)));
        acc[0][cf] = __builtin_amdgcn_mfma_f32_16x16x32_f16(ah[k], bh, acc[0][cf], 0, 0, 0);
        acc[1][cf] = __builtin_amdgcn_mfma_f32_16x16x32_f16(ah[4 + k], bh, acc[1][cf], 0, 0, 0);
      }
    __builtin_amdgcn_s_setprio(0);

    // ---- epilogue: e = relu(acc+b2).W3 -> affine -> fixed-point atomic segsum ----
    float p[2][4] = {{0.f, 0.f, 0.f, 0.f}, {0.f, 0.f, 0.f, 0.f}};
#pragma unroll
    for (int cf = 0; cf < 8; ++cf)
#pragma unroll
      for (int rf = 0; rf < 2; ++rf)
#pragma unroll
        for (int rr = 0; rr < 4; ++rr)
          p[rf][rr] += fmaxf(acc[rf][cf][rr] + b2v[cf], 0.f) * w3v[cf];
#pragma unroll
    for (int m = 1; m < 16; m <<= 1)
#pragma unroll
      for (int rf = 0; rf < 2; ++rf)
#pragma unroll
        for (int rr = 0; rr < 4; ++rr) p[rf][rr] += __shfl_xor(p[rf][rr], m);

    int atom_w[2][4];
#pragma unroll
    for (int rf = 0; rf < 2; ++rf)
#pragma unroll
      for (int rr = 0; rr < 4; ++rr)
        atom_w[rf][rr] = __shfl(cur_perm, rf * 16 + chunk * 4 + rr);

    if (r0 == 0) {
#pragma unroll
      for (int rf = 0; rf < 2; ++rf)
#pragma unroll
        for (int rr = 0; rr < 4; ++rr) {
          int a = atom_w[rf][rr];
          if (a >= 0) {
            float ev = sl * (p[rf][rr] + bb) + ic;
            long long q = llrintf(ev * FIXSCALE);
            atomicAdd(&acc64[img[a]], (unsigned long long)q);
          }
        }
    }

    cur_perm = nperm;
  }
}

// ---------- kernel 5: finalize (int64 fixed-point -> float) ----------
__global__ void finalize_kernel(const unsigned long long* __restrict__ acc64,
                                float* __restrict__ out) {
  int b = blockIdx.x * 256 + threadIdx.x;
  if (b < NIMG)
    out[b] = (float)((double)(long long)acc64[b] * (1.0 / (double)FIXSCALE));
}

extern "C" void kernel_launch(void* const* d_in, const int* in_sizes, int n_in,
                              void* d_out, int out_size, void* d_ws, size_t ws_size,
                              hipStream_t stream) {
  const float* x         = (const float*)d_in[0];
  const float* W1        = (const float*)d_in[1];
  const float* b1        = (const float*)d_in[2];
  const float* W2        = (const float*)d_in[3];
  const float* b2        = (const float*)d_in[4];
  const float* W3        = (const float*)d_in[5];
  const float* b3        = (const float*)d_in[6];
  const float* slope     = (const float*)d_in[7];
  const float* intercept = (const float*)d_in[8];
  const int* sym         = (const int*)d_in[9];
  const int* img         = (const int*)d_in[10];

  char* ws = (char*)d_ws;
  int* wbh    = (int*)ws;                          // 16384 B
  int* bases  = (int*)(ws + 16384);                // 16384 B
  int* offs   = (int*)(ws + 32768);                // 64 B
  int* perm   = (int*)(ws + 32832);                // (N+1024)*4 = 1052672 B
  unsigned long long* acc64 = (unsigned long long*)(ws + 32832 + 1052672);  // 8192 B
  unsigned short* wt = (unsigned short*)(ws + 32832 + 1052672 + 8192);      // 256 KB

  hist_kernel<<<1024, 256, 0, stream>>>(sym, wbh);
  fusedprep_kernel<<<514, 256, 0, stream>>>(wbh, bases, offs, perm, W1, W2, wt, acc64);
  scatter_kernel<<<1024, 256, 0, stream>>>(sym, bases, perm);
  mlp_gemm<<<256, 512, 131072, stream>>>(x, wt, perm, offs, b1, b2,
                                         W3, b3, slope, intercept, img, acc64);
  finalize_kernel<<<4, 256, 0, stream>>>(acc64, (float*)d_out);
}

// Round 14
// 63.270 us; speedup vs baseline: 2.2269x; 2.2269x over previous
//
#include <hip/hip_runtime.h>
#include <hip/hip_bf16.h>
#include <stdint.h>

typedef _Float16 f16x8 __attribute__((ext_vector_type(8)));
typedef __fp16 hf2 __attribute__((ext_vector_type(2)));
typedef float f32x4 __attribute__((ext_vector_type(4)));
typedef unsigned int u32x4 __attribute__((ext_vector_type(4)));
typedef unsigned int u32x2 __attribute__((ext_vector_type(2)));

#define N_ATOMS 262144
#define NSYM 4
#define NIMG 1024

// ---------- kernel 1: per-block symbol counts ----------
__global__ void hist_kernel(const int* __restrict__ sym, int* __restrict__ wbh) {
  int b = blockIdx.x;
  int i = b * 256 + threadIdx.x;
  int lane = threadIdx.x & 63, wave = threadIdx.x >> 6;
  __shared__ int wcnt[4][NSYM];
  int s = sym[i];
#pragma unroll
  for (int t = 0; t < NSYM; ++t) {
    unsigned long long m = __ballot(s == t);
    if (lane == 0) wcnt[wave][t] = __popcll(m);
  }
  __syncthreads();
  if (threadIdx.x < NSYM)
    wbh[b * 4 + threadIdx.x] = wcnt[0][threadIdx.x] + wcnt[1][threadIdx.x] +
                               wcnt[2][threadIdx.x] + wcnt[3][threadIdx.x];
}

// ---------- kernel 2 (fused): block 0 = scan->offsets/bases/pad-fill;
//            blocks 1..512 = wconv (fp16 pre-swizzled planes) ----------
__global__ void fusedprep_kernel(const int* __restrict__ wbh, int* __restrict__ bases,
                                 int* __restrict__ offs, int* __restrict__ perm,
                                 const float* __restrict__ W1, const float* __restrict__ W2,
                                 unsigned short* __restrict__ wt) {
  if (blockIdx.x >= 1) {
    int idx = (blockIdx.x - 1) * 256 + threadIdx.x;  // 0..131071
    int t = idx >> 14;
    int layer = t >> 2, s = t & 3;
    int rem = idx & 16383;
    int h = rem >> 7, u = rem & 127;
    int gs = u >> 3, j = u & 7;
    int d = ((gs ^ (h & 7)) << 3) + j;
    const float* W = layer ? W2 : W1;
    _Float16 hv = (_Float16)W[(s * 128 + d) * 128 + h];  // RNE
    wt[t * 16384 + h * 128 + u] = __builtin_bit_cast(unsigned short, hv);
    return;
  }
  // blockIdx 0: offsets scan
  __shared__ int wtot[4][NSYM];
  __shared__ int offsh[NSYM + 1];
  __shared__ int totsh[NSYM];
  int t = threadIdx.x, lane = t & 63, wave = t >> 6;
  int pre[4][NSYM];
  int sum[NSYM] = {0, 0, 0, 0};
#pragma unroll
  for (int k = 0; k < 4; ++k)
#pragma unroll
    for (int s2 = 0; s2 < NSYM; ++s2) {
      pre[k][s2] = sum[s2];
      sum[s2] += wbh[(t * 4 + k) * 4 + s2];
    }
  int inc[NSYM] = {sum[0], sum[1], sum[2], sum[3]};
  for (int d = 1; d < 64; d <<= 1) {
#pragma unroll
    for (int s2 = 0; s2 < NSYM; ++s2) {
      int v = __shfl_up(inc[s2], d);
      if (lane >= d) inc[s2] += v;
    }
  }
  if (lane == 63)
#pragma unroll
    for (int s2 = 0; s2 < NSYM; ++s2) wtot[wave][s2] = inc[s2];
  __syncthreads();
  int wb[NSYM];
#pragma unroll
  for (int s2 = 0; s2 < NSYM; ++s2) {
    wb[s2] = 0;
    for (int w = 0; w < wave; ++w) wb[s2] += wtot[w][s2];
  }
  if (t == 255)
#pragma unroll
    for (int s2 = 0; s2 < NSYM; ++s2) totsh[s2] = wb[s2] + inc[s2];
  __syncthreads();
  if (t == 0) {
    int o = 0;
    offsh[0] = 0; offs[0] = 0;
    for (int s2 = 0; s2 < NSYM; ++s2) {
      o += (totsh[s2] + 255) & ~255;
      offsh[s2 + 1] = o; offs[s2 + 1] = o;
    }
  }
  __syncthreads();
#pragma unroll
  for (int k = 0; k < 4; ++k)
#pragma unroll
    for (int s2 = 0; s2 < NSYM; ++s2)
      bases[(t * 4 + k) * 4 + s2] = offsh[s2] + wb[s2] + (inc[s2] - sum[s2]) + pre[k][s2];
  for (int s2 = 0; s2 < NSYM; ++s2) {
    int lo = offsh[s2] + totsh[s2], hi = offsh[s2 + 1];
    for (int i = lo + t; i < hi; i += 256) perm[i] = -1;
  }
}

// ---------- kernel 3: deterministic scatter (perm only) ----------
__global__ void scatter_kernel(const int* __restrict__ sym, const int* __restrict__ bases,
                               int* __restrict__ perm) {
  int b = blockIdx.x;
  int i = b * 256 + threadIdx.x;
  int lane = threadIdx.x & 63, wave = threadIdx.x >> 6;
  __shared__ int wcnt[4][NSYM];
  int s = sym[i];
  unsigned long long mymask = 0;
#pragma unroll
  for (int t = 0; t < NSYM; ++t) {
    unsigned long long m = __ballot(s == t);
    if (lane == 0) wcnt[wave][t] = __popcll(m);
    if (s == t) mymask = m;
  }
  __syncthreads();
  int off = bases[b * 4 + s];
  for (int w = 0; w < wave; ++w) off += wcnt[w][s];
  off += __popcll(mymask & ((1ull << lane) - 1ull));
  perm[off] = i;
}

// ---------- kernel 4: fused 2-layer MLP (round-12 structure, verbatim) ----------
// 256 blocks x 8 waves x 32 atoms. LDS 128KB: W1h[0,32K) W2h[32K,64K) once;
// stage/bounce 8KB/wave. Dense 512B x-row loads; T14 prefetch after bounce
// (under layer2+epilogue). e_atom writes; separate segsum.
__global__ __launch_bounds__(512, 2) void mlp_gemm(
    const float* __restrict__ x, const unsigned short* __restrict__ wt,
    const int* __restrict__ perm, const int* __restrict__ offs,
    const float* __restrict__ b1, const float* __restrict__ b2,
    const float* __restrict__ W3, const float* __restrict__ b3,
    const float* __restrict__ slope, const float* __restrict__ intercept,
    float* __restrict__ e_atom) {
  extern __shared__ char lds[];  // 128 KB

  int s = blockIdx.x >> 6;
  int kblk = blockIdx.x & 63;
  int base = offs[s];
  int T = (offs[s + 1] - base) >> 8;

  int tid = threadIdx.x;
  int wave = tid >> 6, lane = tid & 63;
  int r0 = lane & 15, chunk = lane >> 4;
  int l32 = lane & 31, half = lane >> 5;
  char* stage = lds + 65536 + wave * 8192;

  const unsigned short* w1p = wt + (size_t)(0 + s) * 16384;
  const unsigned short* w2p = wt + (size_t)(4 + s) * 16384;

#pragma unroll
  for (int it = 0; it < 8; ++it) {
    int gb = it * 512 + wave * 64;
    const unsigned short* src = (gb >= 2048) ? (w2p + (size_t)(gb - 2048 + lane) * 8)
                                             : (w1p + (size_t)(gb + lane) * 8);
    __builtin_amdgcn_global_load_lds((const unsigned int*)src,
                                     (unsigned int*)(lds + (size_t)gb * 16), 16, 0, 0);
  }

  float b1v[8], b2v[8], w3v[8];
#pragma unroll
  for (int cf = 0; cf < 8; ++cf) {
    b1v[cf] = b1[s * 128 + cf * 16 + r0];
    b2v[cf] = b2[s * 128 + cf * 16 + r0];
    w3v[cf] = W3[s * 128 + cf * 16 + r0];
  }
  float sl = slope[s], ic = intercept[s], bb = b3[s];

  int cur_perm = (kblk < T) ? perm[base + (kblk << 8) + wave * 32 + l32] : -1;
  float4 raw[16];
#pragma unroll
  for (int it = 0; it < 16; ++it) {
    int atom = __shfl(cur_perm, it * 2 + half);
    raw[it] = *(const float4*)(x + (size_t)(atom < 0 ? 0 : atom) * 128 + l32 * 4);
  }

  __syncthreads();  // W staged

  f32x4 zero4 = {0.f, 0.f, 0.f, 0.f};

  for (int t = kblk; t < T; t += 64) {
    int tn = t + 64;
    int nperm = -1;
    if (tn < T) nperm = perm[base + (tn << 8) + wave * 32 + l32];

    // ---- stage-write: cvt fp16 + swizzled ds_write ----
#pragma unroll
    for (int it = 0; it < 16; ++it) {
      int row = it * 2 + half;
      hf2 p0 = __builtin_amdgcn_cvt_pkrtz(raw[it].x, raw[it].y);
      hf2 p1 = __builtin_amdgcn_cvt_pkrtz(raw[it].z, raw[it].w);
      u32x2 w2 = {__builtin_bit_cast(unsigned int, p0), __builtin_bit_cast(unsigned int, p1)};
      int gs = (l32 >> 1) ^ (row & 7);
      *(u32x2*)(stage + row * 256 + gs * 16 + (l32 & 1) * 8) = w2;
    }
    // ---- stage-read: A fragments ----
    f16x8 ah[8];
#pragma unroll
    for (int rf = 0; rf < 2; ++rf)
#pragma unroll
      for (int kk = 0; kk < 4; ++kk) {
        int row = rf * 16 + r0;
        ah[rf * 4 + kk] = *(const f16x8*)(stage + row * 256 +
                                          (((kk * 4 + chunk) ^ (row & 7)) << 4));
      }

    // ---- layer 1: acc = x * W1h, k-outer / cf-inner ----
    f32x4 acc[2][8];
#pragma unroll
    for (int i = 0; i < 2; ++i)
#pragma unroll
      for (int j = 0; j < 8; ++j) acc[i][j] = zero4;

#pragma unroll
    for (int k = 0; k < 4; ++k)
#pragma unroll
      for (int cf = 0; cf < 8; ++cf) {
        int row = cf * 16 + r0;
        f16x8 bh = *(const f16x8*)(lds + row * 256 +
                                   ((((k * 4 + chunk)) << 4) ^ ((row & 7) << 4)));
        acc[0][cf] = __builtin_amdgcn_mfma_f32_16x16x32_f16(ah[k], bh, acc[0][cf], 0, 0, 0);
        acc[1][cf] = __builtin_amdgcn_mfma_f32_16x16x32_f16(ah[4 + k], bh, acc[1][cf], 0, 0, 0);
      }

    // ---- bounce: h1 = relu(acc+b1) -> fp16, 2 half-passes ----
#pragma unroll
    for (int hp2 = 0; hp2 < 2; ++hp2) {
#pragma unroll
      for (int cf4 = 0; cf4 < 4; ++cf4) {
        int cf = hp2 * 4 + cf4;
        float bias = b1v[cf];
        int colp = cf4 * 16 + r0;
#pragma unroll
        for (int rf = 0; rf < 2; ++rf)
#pragma unroll
          for (int rr = 0; rr < 4; ++rr) {
            int row = rf * 16 + chunk * 4 + rr;
            float v = fmaxf(acc[rf][cf][rr] + bias, 0.f);
            unsigned short h = __builtin_bit_cast(unsigned short, (_Float16)v);  // RNE
            int cc = colp ^ (chunk << 4) ^ (rr << 2);
            *(unsigned int*)(stage + row * 256 + cc * 4) = ((unsigned int)h << 16) | h;
          }
      }
#pragma unroll
      for (int kk2 = 0; kk2 < 2; ++kk2) {
        int kk = hp2 * 2 + kk2;
#pragma unroll
        for (int rf = 0; rf < 2; ++rf) {
          int row = rf * 16 + r0;
          int xr3 = ((r0 >> 2) << 4) ^ ((r0 & 3) << 2);
          int c0 = kk2 * 32 + chunk * 8;
          u32x4 pa = *(const u32x4*)(stage + row * 256 + (c0 ^ xr3) * 4);
          u32x4 pb = *(const u32x4*)(stage + row * 256 + ((c0 + 4) ^ xr3) * 4);
          unsigned int h01 = (pa[0] >> 16) | (pa[1] & 0xffff0000u);
          unsigned int h23 = (pa[2] >> 16) | (pa[3] & 0xffff0000u);
          unsigned int h45 = (pb[0] >> 16) | (pb[1] & 0xffff0000u);
          unsigned int h67 = (pb[2] >> 16) | (pb[3] & 0xffff0000u);
          u32x4 hq = {h01, h23, h45, h67};
          ah[rf * 4 + kk] = __builtin_bit_cast(f16x8, hq);
        }
      }
    }

    // ---- T14: issue next tile's dense row loads (land under layer2+epilogue) ----
    if (tn < T) {
#pragma unroll
      for (int it = 0; it < 16; ++it) {
        int atom = __shfl(nperm, it * 2 + half);
        raw[it] = *(const float4*)(x + (size_t)(atom < 0 ? 0 : atom) * 128 + l32 * 4);
      }
    }

    // ---- layer 2: acc = h1 * W2h ----
#pragma unroll
    for (int i = 0; i < 2; ++i)
#pragma unroll
      for (int j = 0; j < 8; ++j) acc[i][j] = zero4;

#pragma unroll
    for (int k = 0; k < 4; ++k)
#pragma unroll
      for (int cf = 0; cf < 8; ++cf) {
        int row = cf * 16 + r0;
        f16x8 bh = *(const f16x8*)(lds + 32768 + row * 256 +
                                   ((((k * 4 + chunk)) << 4) ^ ((row & 7) << 4)));
        acc[0][cf] = __builtin_amdgcn_mfma_f32_16x16x32_f16(ah[k], bh, acc[0][cf], 0, 0, 0);
        acc[1][cf] = __builtin_amdgcn_mfma_f32_16x16x32_f16(ah[4 + k], bh, acc[1][cf], 0, 0, 0);
      }

    // ---- epilogue: e = relu(acc+b2).W3, affine, scatter ----
    float p[2][4] = {{0.f, 0.f, 0.f, 0.f}, {0.f, 0.f, 0.f, 0.f}};
#pragma unroll
    for (int cf = 0; cf < 8; ++cf)
#pragma unroll
      for (int rf = 0; rf < 2; ++rf)
#pragma unroll
        for (int rr = 0; rr < 4; ++rr)
          p[rf][rr] += fmaxf(acc[rf][cf][rr] + b2v[cf], 0.f) * w3v[cf];
#pragma unroll
    for (int m = 1; m < 16; m <<= 1)
#pragma unroll
      for (int rf = 0; rf < 2; ++rf)
#pragma unroll
        for (int rr = 0; rr < 4; ++rr) p[rf][rr] += __shfl_xor(p[rf][rr], m);

    int atom_w[2][4];
#pragma unroll
    for (int rf = 0; rf < 2; ++rf)
#pragma unroll
      for (int rr = 0; rr < 4; ++rr)
        atom_w[rf][rr] = __shfl(cur_perm, rf * 16 + chunk * 4 + rr);

    if (r0 == 0) {
#pragma unroll
      for (int rf = 0; rf < 2; ++rf)
#pragma unroll
        for (int rr = 0; rr < 4; ++rr)
          if (atom_w[rf][rr] >= 0)
            e_atom[atom_w[rf][rr]] = sl * (p[rf][rr] + bb) + ic;
    }

    cur_perm = nperm;
  }
}

// ---------- kernel 5: deterministic per-image segment sum ----------
__global__ void segsum_kernel(const float* __restrict__ e_atom, const int* __restrict__ img,
                              float* __restrict__ out, int n) {
  int b = blockIdx.x;
  int lo = 0, hi = n;
  while (lo < hi) { int m = (lo + hi) >> 1; if (img[m] < b) lo = m + 1; else hi = m; }
  int lo2 = lo, hi2 = n;
  while (lo2 < hi2) { int m = (lo2 + hi2) >> 1; if (img[m] < b + 1) lo2 = m + 1; else hi2 = m; }
  float sum = 0.f;
  for (int i = lo + threadIdx.x; i < lo2; i += blockDim.x) sum += e_atom[i];
  for (int m = 32; m; m >>= 1) sum += __shfl_down(sum, m);
  __shared__ float part[4];
  int lane = threadIdx.x & 63, wave = threadIdx.x >> 6;
  if (lane == 0) part[wave] = sum;
  __syncthreads();
  if (threadIdx.x == 0) out[b] = part[0] + part[1] + part[2] + part[3];
}

extern "C" void kernel_launch(void* const* d_in, const int* in_sizes, int n_in,
                              void* d_out, int out_size, void* d_ws, size_t ws_size,
                              hipStream_t stream) {
  const float* x         = (const float*)d_in[0];
  const float* W1        = (const float*)d_in[1];
  const float* b1        = (const float*)d_in[2];
  const float* W2        = (const float*)d_in[3];
  const float* b2        = (const float*)d_in[4];
  const float* W3        = (const float*)d_in[5];
  const float* b3        = (const float*)d_in[6];
  const float* slope     = (const float*)d_in[7];
  const float* intercept = (const float*)d_in[8];
  const int* sym         = (const int*)d_in[9];
  const int* img         = (const int*)d_in[10];

  char* ws = (char*)d_ws;
  int* wbh    = (int*)ws;                          // 16384 B
  int* bases  = (int*)(ws + 16384);                // 16384 B
  int* offs   = (int*)(ws + 32768);                // 64 B
  int* perm   = (int*)(ws + 32832);                // (N+1024)*4 = 1052672 B
  float* e_atom = (float*)(ws + 32832 + 1052672);  // N*4
  unsigned short* wt = (unsigned short*)(ws + 32832 + 1052672 + 1048576);  // 256 KB

  hist_kernel<<<1024, 256, 0, stream>>>(sym, wbh);
  fusedprep_kernel<<<513, 256, 0, stream>>>(wbh, bases, offs, perm, W1, W2, wt);
  scatter_kernel<<<1024, 256, 0, stream>>>(sym, bases, perm);
  mlp_gemm<<<256, 512, 131072, stream>>>(x, wt, perm, offs, b1, b2,
                                         W3, b3, slope, intercept, e_atom);
  segsum_kernel<<<NIMG, 256, 0, stream>>>(e_atom, img, (float*)d_out, N_ATOMS);
}

// Round 15
// 62.731 us; speedup vs baseline: 2.2461x; 1.0086x over previous
//
#include <hip/hip_runtime.h>
#include <hip/hip_bf16.h>
#include <stdint.h>

typedef _Float16 f16x8 __attribute__((ext_vector_type(8)));
typedef _Float16 f16x4 __attribute__((ext_vector_type(4)));
typedef __fp16 hf2 __attribute__((ext_vector_type(2)));
typedef float f32x4 __attribute__((ext_vector_type(4)));
typedef unsigned int u32x4 __attribute__((ext_vector_type(4)));
typedef unsigned int u32x2 __attribute__((ext_vector_type(2)));

#define N_ATOMS 262144
#define NSYM 4
#define NIMG 1024

// ---------- kernel 1: per-block symbol counts ----------
__global__ void hist_kernel(const int* __restrict__ sym, int* __restrict__ wbh) {
  int b = blockIdx.x;
  int i = b * 256 + threadIdx.x;
  int lane = threadIdx.x & 63, wave = threadIdx.x >> 6;
  __shared__ int wcnt[4][NSYM];
  int s = sym[i];
#pragma unroll
  for (int t = 0; t < NSYM; ++t) {
    unsigned long long m = __ballot(s == t);
    if (lane == 0) wcnt[wave][t] = __popcll(m);
  }
  __syncthreads();
  if (threadIdx.x < NSYM)
    wbh[b * 4 + threadIdx.x] = wcnt[0][threadIdx.x] + wcnt[1][threadIdx.x] +
                               wcnt[2][threadIdx.x] + wcnt[3][threadIdx.x];
}

// ---------- kernel 2 (fused): block 0 = scan->offsets/bases/pad-fill;
//  blocks 1..512 = weight conversion:
//   planes t=0..3  : W1 fp16 [h][d], granule-XOR pre-swizzled (K=32 B/A-frag)
//   planes t=4..7  : W2 fp16 K=16-B-frag layout: w2k[h2][unit U'][e], where
//     U = U' ^ (h2&7); p=U>>2; c=U&3; cf=2p+(e>>2); j=e&3; h1=cf*16+c*4+j
__global__ void fusedprep_kernel(const int* __restrict__ wbh, int* __restrict__ bases,
                                 int* __restrict__ offs, int* __restrict__ perm,
                                 const float* __restrict__ W1, const float* __restrict__ W2,
                                 unsigned short* __restrict__ wt) {
  if (blockIdx.x >= 1) {
    int idx = (blockIdx.x - 1) * 256 + threadIdx.x;  // 0..131071
    int t = idx >> 14;
    int rem = idx & 16383;
    if (t < 4) {
      int s = t;
      int h = rem >> 7, u = rem & 127;
      int gs = u >> 3, j = u & 7;
      int d = ((gs ^ (h & 7)) << 3) + j;
      _Float16 hv = (_Float16)W1[(s * 128 + d) * 128 + h];  // RNE
      wt[t * 16384 + h * 128 + u] = __builtin_bit_cast(unsigned short, hv);
    } else {
      int s = t - 4;
      int h2 = rem >> 7, q = rem & 127;
      int Up = q >> 3, e = q & 7;
      int U = Up ^ (h2 & 7);
      int p = U >> 2, c = U & 3;
      int cf = 2 * p + (e >> 2), j = e & 3;
      int h1 = cf * 16 + c * 4 + j;
      _Float16 hv = (_Float16)W2[(s * 128 + h1) * 128 + h2];  // RNE
      wt[t * 16384 + h2 * 128 + q] = __builtin_bit_cast(unsigned short, hv);
    }
    return;
  }
  // blockIdx 0: offsets scan
  __shared__ int wtot[4][NSYM];
  __shared__ int offsh[NSYM + 1];
  __shared__ int totsh[NSYM];
  int t = threadIdx.x, lane = t & 63, wave = t >> 6;
  int pre[4][NSYM];
  int sum[NSYM] = {0, 0, 0, 0};
#pragma unroll
  for (int k = 0; k < 4; ++k)
#pragma unroll
    for (int s2 = 0; s2 < NSYM; ++s2) {
      pre[k][s2] = sum[s2];
      sum[s2] += wbh[(t * 4 + k) * 4 + s2];
    }
  int inc[NSYM] = {sum[0], sum[1], sum[2], sum[3]};
  for (int d = 1; d < 64; d <<= 1) {
#pragma unroll
    for (int s2 = 0; s2 < NSYM; ++s2) {
      int v = __shfl_up(inc[s2], d);
      if (lane >= d) inc[s2] += v;
    }
  }
  if (lane == 63)
#pragma unroll
    for (int s2 = 0; s2 < NSYM; ++s2) wtot[wave][s2] = inc[s2];
  __syncthreads();
  int wb[NSYM];
#pragma unroll
  for (int s2 = 0; s2 < NSYM; ++s2) {
    wb[s2] = 0;
    for (int w = 0; w < wave; ++w) wb[s2] += wtot[w][s2];
  }
  if (t == 255)
#pragma unroll
    for (int s2 = 0; s2 < NSYM; ++s2) totsh[s2] = wb[s2] + inc[s2];
  __syncthreads();
  if (t == 0) {
    int o = 0;
    offsh[0] = 0; offs[0] = 0;
    for (int s2 = 0; s2 < NSYM; ++s2) {
      o += (totsh[s2] + 255) & ~255;
      offsh[s2 + 1] = o; offs[s2 + 1] = o;
    }
  }
  __syncthreads();
#pragma unroll
  for (int k = 0; k < 4; ++k)
#pragma unroll
    for (int s2 = 0; s2 < NSYM; ++s2)
      bases[(t * 4 + k) * 4 + s2] = offsh[s2] + wb[s2] + (inc[s2] - sum[s2]) + pre[k][s2];
  for (int s2 = 0; s2 < NSYM; ++s2) {
    int lo = offsh[s2] + totsh[s2], hi = offsh[s2 + 1];
    for (int i = lo + t; i < hi; i += 256) perm[i] = -1;
  }
}

// ---------- kernel 3: deterministic scatter (perm only) ----------
__global__ void scatter_kernel(const int* __restrict__ sym, const int* __restrict__ bases,
                               int* __restrict__ perm) {
  int b = blockIdx.x;
  int i = b * 256 + threadIdx.x;
  int lane = threadIdx.x & 63, wave = threadIdx.x >> 6;
  __shared__ int wcnt[4][NSYM];
  int s = sym[i];
  unsigned long long mymask = 0;
#pragma unroll
  for (int t = 0; t < NSYM; ++t) {
    unsigned long long m = __ballot(s == t);
    if (lane == 0) wcnt[wave][t] = __popcll(m);
    if (s == t) mymask = m;
  }
  __syncthreads();
  int off = bases[b * 4 + s];
  for (int w = 0; w < wave; ++w) off += wcnt[w][s];
  off += __popcll(mymask & ((1ull << lane) - 1ull));
  perm[off] = i;
}

// ---------- kernel 4: fused 2-layer MLP, bounce-free ----------
// Layer 1 SWAPPED: acc = mfma(W1frag, xfrag) -> lane holds h1^T:
//   h1[atom = rf*16+r0][h1 = cf*16+chunk*4+rr]  (same LDS reads as before)
// Layer 2 uses K=16 mfma_f32_16x16x16f16: its A-frag layout (row=r0=atom,
//   k=chunk*4+j) EXACTLY matches the packed L1 output -> h1 never touches LDS.
__global__ __launch_bounds__(512, 2) void mlp_gemm(
    const float* __restrict__ x, const unsigned short* __restrict__ wt,
    const int* __restrict__ perm, const int* __restrict__ offs,
    const float* __restrict__ b1, const float* __restrict__ b2,
    const float* __restrict__ W3, const float* __restrict__ b3,
    const float* __restrict__ slope, const float* __restrict__ intercept,
    float* __restrict__ e_atom) {
  extern __shared__ char lds[];  // 128 KB: W1[0,32K) w2k[32K,64K) stage 8K/wave

  int s = blockIdx.x >> 6;
  int kblk = blockIdx.x & 63;
  int base = offs[s];
  int T = (offs[s + 1] - base) >> 8;

  int tid = threadIdx.x;
  int wave = tid >> 6, lane = tid & 63;
  int r0 = lane & 15, chunk = lane >> 4;
  int l32 = lane & 31, half = lane >> 5;
  char* stage = lds + 65536 + wave * 8192;

  const unsigned short* w1p = wt + (size_t)(0 + s) * 16384;
  const unsigned short* w2p = wt + (size_t)(4 + s) * 16384;

#pragma unroll
  for (int it = 0; it < 8; ++it) {
    int gb = it * 512 + wave * 64;
    const unsigned short* src = (gb >= 2048) ? (w2p + (size_t)(gb - 2048 + lane) * 8)
                                             : (w1p + (size_t)(gb + lane) * 8);
    __builtin_amdgcn_global_load_lds((const unsigned int*)src,
                                     (unsigned int*)(lds + (size_t)gb * 16), 16, 0, 0);
  }

  // per-symbol constants: b1 as float4 (h1 = cf*16 + chunk*4 + rr); b2/W3 by col
  float4 b1q[8];
  float b2v[8], w3v[8];
#pragma unroll
  for (int cf = 0; cf < 8; ++cf) {
    b1q[cf] = *(const float4*)(b1 + s * 128 + cf * 16 + chunk * 4);
    b2v[cf] = b2[s * 128 + cf * 16 + r0];
    w3v[cf] = W3[s * 128 + cf * 16 + r0];
  }
  float sl = slope[s], ic = intercept[s], bb = b3[s];

  int cur_perm = (kblk < T) ? perm[base + (kblk << 8) + wave * 32 + l32] : -1;
  float4 raw[16];
#pragma unroll
  for (int it = 0; it < 16; ++it) {
    int atom = __shfl(cur_perm, it * 2 + half);
    raw[it] = *(const float4*)(x + (size_t)(atom < 0 ? 0 : atom) * 128 + l32 * 4);
  }

  __syncthreads();  // W staged

  f32x4 zero4 = {0.f, 0.f, 0.f, 0.f};

  for (int t = kblk; t < T; t += 64) {
    int tn = t + 64;
    int nperm = -1;
    if (tn < T) nperm = perm[base + (tn << 8) + wave * 32 + l32];

    // ---- stage-write: cvt fp16 + swizzled ds_write ----
#pragma unroll
    for (int it = 0; it < 16; ++it) {
      int row = it * 2 + half;
      hf2 p0 = __builtin_amdgcn_cvt_pkrtz(raw[it].x, raw[it].y);
      hf2 p1 = __builtin_amdgcn_cvt_pkrtz(raw[it].z, raw[it].w);
      u32x2 w2 = {__builtin_bit_cast(unsigned int, p0), __builtin_bit_cast(unsigned int, p1)};
      int gs = (l32 >> 1) ^ (row & 7);
      *(u32x2*)(stage + row * 256 + gs * 16 + (l32 & 1) * 8) = w2;
    }
    // ---- stage-read: x fragments (B-operand of swapped L1) ----
    f16x8 ah[8];
#pragma unroll
    for (int rf = 0; rf < 2; ++rf)
#pragma unroll
      for (int kk = 0; kk < 4; ++kk) {
        int row = rf * 16 + r0;
        ah[rf * 4 + kk] = *(const f16x8*)(stage + row * 256 +
                                          (((kk * 4 + chunk) ^ (row & 7)) << 4));
      }

    // ---- layer 1 SWAPPED: acc[rf][cf] = W1tile(cf)^T-frag x xtile(rf) ----
    f32x4 acc[2][8];
#pragma unroll
    for (int i = 0; i < 2; ++i)
#pragma unroll
      for (int j = 0; j < 8; ++j) acc[i][j] = zero4;

#pragma unroll
    for (int k = 0; k < 4; ++k)
#pragma unroll
      for (int cf = 0; cf < 8; ++cf) {
        int row = cf * 16 + r0;
        f16x8 bh = *(const f16x8*)(lds + row * 256 +
                                   ((((k * 4 + chunk)) << 4) ^ ((row & 7) << 4)));
        acc[0][cf] = __builtin_amdgcn_mfma_f32_16x16x32_f16(bh, ah[k], acc[0][cf], 0, 0, 0);
        acc[1][cf] = __builtin_amdgcn_mfma_f32_16x16x32_f16(bh, ah[4 + k], acc[1][cf], 0, 0, 0);
      }

    // ---- pack: ah2[rf][cf] = fp16 RNE relu(acc + b1), in-register (no LDS) ----
    u32x2 ah2[2][8];
#pragma unroll
    for (int rf = 0; rf < 2; ++rf)
#pragma unroll
      for (int cf = 0; cf < 8; ++cf) {
        float v0 = fmaxf(acc[rf][cf][0] + b1q[cf].x, 0.f);
        float v1 = fmaxf(acc[rf][cf][1] + b1q[cf].y, 0.f);
        float v2 = fmaxf(acc[rf][cf][2] + b1q[cf].z, 0.f);
        float v3 = fmaxf(acc[rf][cf][3] + b1q[cf].w, 0.f);
        unsigned int h0 = __builtin_bit_cast(unsigned short, (_Float16)v0);
        unsigned int h1 = __builtin_bit_cast(unsigned short, (_Float16)v1);
        unsigned int h2 = __builtin_bit_cast(unsigned short, (_Float16)v2);
        unsigned int h3 = __builtin_bit_cast(unsigned short, (_Float16)v3);
        u32x2 pk = {h0 | (h1 << 16), h2 | (h3 << 16)};
        ah2[rf][cf] = pk;
      }

    // ---- T14: issue next tile's dense row loads (land under layer2+epilogue) ----
    if (tn < T) {
#pragma unroll
      for (int it = 0; it < 16; ++it) {
        int atom = __shfl(nperm, it * 2 + half);
        raw[it] = *(const float4*)(x + (size_t)(atom < 0 ? 0 : atom) * 128 + l32 * 4);
      }
    }

    // ---- layer 2: K=16 MFMA, A = ah2 (registers), B = w2k from LDS ----
    f32x4 acc2[2][8];
#pragma unroll
    for (int i = 0; i < 2; ++i)
#pragma unroll
      for (int j = 0; j < 8; ++j) acc2[i][j] = zero4;

#pragma unroll
    for (int p = 0; p < 4; ++p)
#pragma unroll
      for (int t2 = 0; t2 < 8; ++t2) {
        int row = t2 * 16 + r0;
        f16x8 w = *(const f16x8*)(lds + 32768 + row * 256 +
                                  (((p * 4 + chunk) ^ (r0 & 7)) << 4));
        f16x4 blo = __builtin_shufflevector(w, w, 0, 1, 2, 3);
        f16x4 bhi = __builtin_shufflevector(w, w, 4, 5, 6, 7);
        acc2[0][t2] = __builtin_amdgcn_mfma_f32_16x16x16f16(
            __builtin_bit_cast(f16x4, ah2[0][2 * p]), blo, acc2[0][t2], 0, 0, 0);
        acc2[1][t2] = __builtin_amdgcn_mfma_f32_16x16x16f16(
            __builtin_bit_cast(f16x4, ah2[1][2 * p]), blo, acc2[1][t2], 0, 0, 0);
        acc2[0][t2] = __builtin_amdgcn_mfma_f32_16x16x16f16(
            __builtin_bit_cast(f16x4, ah2[0][2 * p + 1]), bhi, acc2[0][t2], 0, 0, 0);
        acc2[1][t2] = __builtin_amdgcn_mfma_f32_16x16x16f16(
            __builtin_bit_cast(f16x4, ah2[1][2 * p + 1]), bhi, acc2[1][t2], 0, 0, 0);
      }

    // ---- epilogue: e = relu(acc2+b2).W3, affine, scatter (layout unchanged) ----
    float p2[2][4] = {{0.f, 0.f, 0.f, 0.f}, {0.f, 0.f, 0.f, 0.f}};
#pragma unroll
    for (int t2 = 0; t2 < 8; ++t2)
#pragma unroll
      for (int rf = 0; rf < 2; ++rf)
#pragma unroll
        for (int rr = 0; rr < 4; ++rr)
          p2[rf][rr] += fmaxf(acc2[rf][t2][rr] + b2v[t2], 0.f) * w3v[t2];
#pragma unroll
    for (int m = 1; m < 16; m <<= 1)
#pragma unroll
      for (int rf = 0; rf < 2; ++rf)
#pragma unroll
        for (int rr = 0; rr < 4; ++rr) p2[rf][rr] += __shfl_xor(p2[rf][rr], m);

    int atom_w[2][4];
#pragma unroll
    for (int rf = 0; rf < 2; ++rf)
#pragma unroll
      for (int rr = 0; rr < 4; ++rr)
        atom_w[rf][rr] = __shfl(cur_perm, rf * 16 + chunk * 4 + rr);

    if (r0 == 0) {
#pragma unroll
      for (int rf = 0; rf < 2; ++rf)
#pragma unroll
        for (int rr = 0; rr < 4; ++rr)
          if (atom_w[rf][rr] >= 0)
            e_atom[atom_w[rf][rr]] = sl * (p2[rf][rr] + bb) + ic;
    }

    cur_perm = nperm;
  }
}

// ---------- kernel 5: deterministic per-image segment sum ----------
__global__ void segsum_kernel(const float* __restrict__ e_atom, const int* __restrict__ img,
                              float* __restrict__ out, int n) {
  int b = blockIdx.x;
  int lo = 0, hi = n;
  while (lo < hi) { int m = (lo + hi) >> 1; if (img[m] < b) lo = m + 1; else hi = m; }
  int lo2 = lo, hi2 = n;
  while (lo2 < hi2) { int m = (lo2 + hi2) >> 1; if (img[m] < b + 1) lo2 = m + 1; else hi2 = m; }
  float sum = 0.f;
  for (int i = lo + threadIdx.x; i < lo2; i += blockDim.x) sum += e_atom[i];
  for (int m = 32; m; m >>= 1) sum += __shfl_down(sum, m);
  __shared__ float part[4];
  int lane = threadIdx.x & 63, wave = threadIdx.x >> 6;
  if (lane == 0) part[wave] = sum;
  __syncthreads();
  if (threadIdx.x == 0) out[b] = part[0] + part[1] + part[2] + part[3];
}

extern "C" void kernel_launch(void* const* d_in, const int* in_sizes, int n_in,
                              void* d_out, int out_size, void* d_ws, size_t ws_size,
                              hipStream_t stream) {
  const float* x         = (const float*)d_in[0];
  const float* W1        = (const float*)d_in[1];
  const float* b1        = (const float*)d_in[2];
  const float* W2        = (const float*)d_in[3];
  const float* b2        = (const float*)d_in[4];
  const float* W3        = (const float*)d_in[5];
  const float* b3        = (const float*)d_in[6];
  const float* slope     = (const float*)d_in[7];
  const float* intercept = (const float*)d_in[8];
  const int* sym         = (const int*)d_in[9];
  const int* img         = (const int*)d_in[10];

  char* ws = (char*)d_ws;
  int* wbh    = (int*)ws;                          // 16384 B
  int* bases  = (int*)(ws + 16384);                // 16384 B
  int* offs   = (int*)(ws + 32768);                // 64 B
  int* perm   = (int*)(ws + 32832);                // (N+1024)*4 = 1052672 B
  float* e_atom = (float*)(ws + 32832 + 1052672);  // N*4
  unsigned short* wt = (unsigned short*)(ws + 32832 + 1052672 + 1048576);  // 256 KB

  hist_kernel<<<1024, 256, 0, stream>>>(sym, wbh);
  fusedprep_kernel<<<513, 256, 0, stream>>>(wbh, bases, offs, perm, W1, W2, wt);
  scatter_kernel<<<1024, 256, 0, stream>>>(sym, bases, perm);
  mlp_gemm<<<256, 512, 131072, stream>>>(x, wt, perm, offs, b1, b2,
                                         W3, b3, slope, intercept, e_atom);
  segsum_kernel<<<NIMG, 256, 0, stream>>>(e_atom, img, (float*)d_out, N_ATOMS);
}